// Round 1
// baseline (729.184 us; speedup 1.0000x reference)
//
#include <hip/hip_runtime.h>
#include <math.h>

constexpr int B_ = 4;
constexpr int S_ = 2048;
constexpr int H_ = 16;
constexpr int HID_ = 2048;
constexpr int DK_ = 128;
constexpr int DV_ = 128;

constexpr int CH_ = 16;              // timesteps per LDS chunk
constexpr int NC_ = 4;               // DV split across blocks
constexpr int COLS_ = DV_ / NC_;     // 32 columns per block
constexpr int NCHS_ = S_ / CH_;      // 128 chunks

// ---------------- DPP cross-lane helpers (VALU-latency, no DS pipe) --------
template <int CTRL>
__device__ __forceinline__ float dpp_add(float x) {
  int y = __builtin_amdgcn_update_dpp(0, __float_as_int(x), CTRL, 0xF, 0xF, true);
  return x + __int_as_float(y);
}
// butterfly sum over aligned 16-lane groups; every lane gets the total
__device__ __forceinline__ float sum16(float x) {
  x = dpp_add<0xB1>(x);   // quad_perm [1,0,3,2]  (xor 1)
  x = dpp_add<0x4E>(x);   // quad_perm [2,3,0,1]  (xor 2)
  x = dpp_add<0x141>(x);  // row_half_mirror      (xor 7)
  x = dpp_add<0x140>(x);  // row_mirror           (xor 15)
  return x;
}
__device__ __forceinline__ float swz_xor16(float x) {
  // BitMode swizzle: lane ^= 16 within each 32-lane group
  int y = __builtin_amdgcn_ds_swizzle(__float_as_int(x), 0x401F);
  return __int_as_float(y);
}

// ---------------------------------------------------------------------------
// Gates: decay/beta for all (b,s,h). Block = 4 rows of BS; wave w covers 8
// output cols (waves 0,1 -> Wa heads 0-7/8-15; waves 2,3 -> Wb heads 0-7/8-15).
// Register tile 4 rows x 8 cols per lane, K split across 64 lanes.
// ---------------------------------------------------------------------------
__global__ __launch_bounds__(256) void gates_kernel(
    const float* __restrict__ x, const float* __restrict__ Wa,
    const float* __restrict__ Wb, const float* __restrict__ dt_bias,
    const float* __restrict__ A_log, float* __restrict__ decay,
    float* __restrict__ beta) {
  const int r0 = blockIdx.x * 4;
  const int w = threadIdx.x >> 6;
  const int lane = threadIdx.x & 63;

  const float4* x4 = reinterpret_cast<const float4*>(x);
  const float4* wbase = reinterpret_cast<const float4*>(w < 2 ? Wa : Wb);
  const int h0 = (w & 1) * 8;

  float acc[4][8];
#pragma unroll
  for (int i = 0; i < 4; ++i)
#pragma unroll
    for (int j = 0; j < 8; ++j) acc[i][j] = 0.f;

  for (int m = 0; m < 8; ++m) {
    const int kk = m * 64 + lane;
    float4 xv[4], wv[8];
#pragma unroll
    for (int i = 0; i < 4; ++i) xv[i] = x4[(size_t)(r0 + i) * (HID_ / 4) + kk];
#pragma unroll
    for (int j = 0; j < 8; ++j) wv[j] = wbase[(size_t)(h0 + j) * (HID_ / 4) + kk];
#pragma unroll
    for (int i = 0; i < 4; ++i)
#pragma unroll
      for (int j = 0; j < 8; ++j) {
        acc[i][j] = fmaf(xv[i].x, wv[j].x, acc[i][j]);
        acc[i][j] = fmaf(xv[i].y, wv[j].y, acc[i][j]);
        acc[i][j] = fmaf(xv[i].z, wv[j].z, acc[i][j]);
        acc[i][j] = fmaf(xv[i].w, wv[j].w, acc[i][j]);
      }
  }

  float myval = 0.f;
#pragma unroll
  for (int i = 0; i < 4; ++i)
#pragma unroll
    for (int j = 0; j < 8; ++j) {
      float v = sum16(acc[i][j]);
      v += __shfl_xor(v, 16, 64);
      v += __shfl_xor(v, 32, 64);
      if (lane == i * 8 + j) myval = v;
    }
  if (lane < 32) {
    const int i = lane >> 3, j = lane & 7;
    const int h = h0 + j;
    const int row = r0 + i;
    if (w < 2) {
      const float za = myval + dt_bias[h];
      const float sp = (za > 20.f) ? za : log1pf(expf(za));
      decay[(size_t)row * H_ + h] = expf(-expf(A_log[h]) * sp);
    } else {
      beta[(size_t)row * H_ + h] = myval;
    }
  }
}

// ---------------------------------------------------------------------------
// Scan. Block = (dv-chunk c, head h, batch b), 512 threads (8 waves ->
// 2 waves/SIMD so dependent-chain latency is hidden by the co-resident wave).
// Lane owns 8 contiguous rows x 1 col of the 128x32 state slice.
// sub = tid&15 (16 lanes per column, DPP sum16 reductions),
// col = tid>>4 (0..31, column relative to chunk).
// k/q LDS layout: per timestep 32 float4 slots, phys = (d4&1)*16 + (d4>>1)
// so fragment reads lk4[u*32 + t*16 + sub] are 16 consecutive float4s.
// out_t = g*(q.s_prev) + (q.k)*delta  -- qk precomputed at staging time.
// ---------------------------------------------------------------------------
__global__ __launch_bounds__(512) void scan_kernel(
    const float* __restrict__ qg, const float* __restrict__ kg,
    const float* __restrict__ vg, const float* __restrict__ decay,
    const float* __restrict__ beta, float* __restrict__ outg) {
  const int c = blockIdx.x;
  const int h = blockIdx.y;
  const int b = blockIdx.z;
  const int tid = threadIdx.x;
  const int sub = tid & 15;
  const int col = tid >> 4;  // 0..31

  __shared__ __align__(16) float lk[CH_ * DK_];
  __shared__ __align__(16) float lq[CH_ * DK_];
  __shared__ __align__(16) float lv[CH_ * COLS_];
  __shared__ __align__(16) float lgbq[CH_ * 4];  // (g, beta, qk, pad) per step

  const float4* k4 = reinterpret_cast<const float4*>(kg);
  const float4* q4 = reinterpret_cast<const float4*>(qg);
  const float4* v4 = reinterpret_cast<const float4*>(vg);
  float4* lk4 = reinterpret_cast<float4*>(lk);
  float4* lq4 = reinterpret_cast<float4*>(lq);
  float4* lv4 = reinterpret_cast<float4*>(lv);

  // staging: thread stages one k/q float4 at (u0, d4)
  const int u0 = tid >> 5, d4 = tid & 31;
  const int ph = (d4 & 1) * 16 + (d4 >> 1);

  float4 pk = {}, pq = {}, pv = {};
  float pg = 0.f, pb = 0.f;

  auto loadRegs = [&](int s0) {
    const size_t base = ((size_t)(b * S_ + s0 + u0) * H_ + h) * (DK_ / 4) + d4;
    pk = k4[base];
    pq = q4[base];
    if (tid < 128) {
      const int uu = tid >> 3, e = tid & 7;
      pv = v4[((size_t)(b * S_ + s0 + uu) * H_ + h) * (DV_ / 4) + c * (COLS_ / 4) + e];
    }
    if (tid >= 128 && tid < 128 + CH_)
      pg = decay[(size_t)(b * S_ + s0 + (tid - 128)) * H_ + h];
    if (tid >= 160 && tid < 160 + CH_)
      pb = beta[(size_t)(b * S_ + s0 + (tid - 160)) * H_ + h];
  };

  auto writeLDS = [&]() {
    lk4[u0 * 32 + ph] = pk;
    lq4[u0 * 32 + ph] = pq;
    if (tid < 128) {
      const int uu = tid >> 3, e = tid & 7;
      lv4[uu * (COLS_ / 4) + e] = pv;
    }
    if (tid >= 128 && tid < 128 + CH_) lgbq[(tid - 128) * 4 + 0] = pg;
    if (tid >= 160 && tid < 160 + CH_) lgbq[(tid - 160) * 4 + 1] = pb;
    // qk[u] = q_u . k_u : per-lane dot4 partials reduced over the 32 lanes of u
    float p = fmaf(pq.x, pk.x, fmaf(pq.y, pk.y, fmaf(pq.z, pk.z, pq.w * pk.w)));
    p = sum16(p);
    p += swz_xor16(p);
    if ((tid & 31) == 0) lgbq[u0 * 4 + 2] = p;
  };

  struct Frag {
    float4 k0, k1, q0, q1, gbq;
    float v;
  };
  auto loadFrag = [&](int u) {
    Frag f;
    f.k0 = lk4[u * 32 + sub];
    f.k1 = lk4[u * 32 + 16 + sub];
    f.q0 = lq4[u * 32 + sub];
    f.q1 = lq4[u * 32 + 16 + sub];
    f.v = lv[u * COLS_ + col];
    f.gbq = *reinterpret_cast<const float4*>(&lgbq[u * 4]);
    return f;
  };

  float st[8];  // st[r]: col col, row sub*8+r
#pragma unroll
  for (int r = 0; r < 8; ++r) st[r] = 0.f;

  auto step = [&](const Frag& f, int u, int s0) {
    const float g = f.gbq.x, bt = f.gbq.y, qk = f.gbq.z;
    const float kr[8] = {f.k0.x, f.k0.y, f.k0.z, f.k0.w, f.k1.x, f.k1.y, f.k1.z, f.k1.w};
    const float qr[8] = {f.q0.x, f.q0.y, f.q0.z, f.q0.w, f.q1.x, f.q1.y, f.q1.z, f.q1.w};
    float vp = 0.f, op = 0.f;
#pragma unroll
    for (int r = 0; r < 8; ++r) {
      vp = fmaf(kr[r], st[r], vp);
      op = fmaf(qr[r], st[r], op);
    }
    vp = sum16(vp);
    op = sum16(op);
    const float dlt = (f.v - g * vp) * bt;
#pragma unroll
    for (int r = 0; r < 8; ++r) st[r] = fmaf(kr[r], dlt, st[r] * g);
    if (sub == 0) {
      __builtin_nontemporal_store(
          fmaf(qk, dlt, g * op),
          &outg[((size_t)(b * S_ + s0 + u) * H_ + h) * DV_ + c * COLS_ + col]);
    }
  };

  loadRegs(0);
  writeLDS();
  __syncthreads();

  for (int ci = 0; ci < NCHS_; ++ci) {
    const int s0 = ci * CH_;
    if (ci + 1 < NCHS_) loadRegs(s0 + CH_);  // global prefetch for next chunk

    Frag cur = loadFrag(0);
    for (int u = 0; u < CH_ - 1; ++u) {
      Frag nxt = loadFrag(u + 1);  // LDS prefetch for next step
      step(cur, u, s0);
      cur = nxt;
    }
    step(cur, CH_ - 1, s0);

    __syncthreads();
    if (ci + 1 < NCHS_) writeLDS();
    __syncthreads();
  }
}

extern "C" void kernel_launch(void* const* d_in, const int* in_sizes, int n_in,
                              void* d_out, int out_size, void* d_ws, size_t ws_size,
                              hipStream_t stream) {
  const float* x = (const float*)d_in[0];
  const float* q = (const float*)d_in[1];
  const float* k = (const float*)d_in[2];
  const float* v = (const float*)d_in[3];
  const float* Wa = (const float*)d_in[4];
  const float* Wb = (const float*)d_in[5];
  const float* dtb = (const float*)d_in[6];
  const float* Alog = (const float*)d_in[7];
  float* out = (float*)d_out;

  float* decay = (float*)d_ws;
  float* beta = decay + (size_t)B_ * S_ * H_;

  gates_kernel<<<B_ * S_ / 4, 256, 0, stream>>>(x, Wa, Wb, dtb, Alog, decay, beta);
  scan_kernel<<<dim3(NC_, H_, B_), 512, 0, stream>>>(q, k, v, decay, beta, out);
}